// Round 4
// baseline (246.331 us; speedup 1.0000x reference)
//
#include <hip/hip_runtime.h>
#include <hip/hip_bf16.h>

#define NN 23
#define XF 92      // 23 nodes * 4 features (2 heads * N_HID 2)
#define NF 128     // fc1 out
#define NP 16      // pre out
#define FSTRIDE 117  // 92 feat + 23 x + 2 pad (odd -> conflict-free LDS)
#define BLK 64

__device__ __forceinline__ float bits2f(unsigned u) { return __uint_as_float(u << 16); }
__device__ __forceinline__ float b2f(__hip_bfloat16 h) {
    union { __hip_bfloat16 h; unsigned short u; } c; c.h = h;
    return bits2f((unsigned)c.u);
}
__device__ __forceinline__ float geluf(float v) {
    return 0.5f * v * (1.0f + erff(v * 0.70710678118654752f));
}

// Detect whether a float-tensor buffer holds f32 (true) or bf16 (false).
// f32-backed: low 16-bit halves are mantissa bits -> mostly "insane" exponents.
// bf16-backed: every half is a sane normal (or zero) -> insane == 0.
__device__ __forceinline__ bool sniff_f32(const void* p) {
    const unsigned* w = (const unsigned*)p;
    int insane = 0;
    #pragma unroll
    for (int k = 0; k < 32; ++k) {
        unsigned v = w[k];
        unsigned h0 = v & 0xFFFFu, h1 = v >> 16;
        int e0 = (int)((h0 >> 7) & 0xFF), e1 = (int)((h1 >> 7) & 0xFF);
        bool s0 = ((h0 & 0x7FFFu) == 0u) || (e0 >= 94 && e0 <= 160);
        bool s1 = ((h1 & 0x7FFFu) == 0u) || (e1 >= 94 && e1 <= 160);
        insane += s0 ? 0 : 1;
        insane += s1 ? 0 : 1;
    }
    return insane >= 8;
}

__device__ __forceinline__ float ld1(const void* p, int i, bool f32) {
    return f32 ? ((const float*)p)[i] : b2f(((const __hip_bfloat16*)p)[i]);
}

__global__ __launch_bounds__(BLK, 1) void gat_fused(
    const void* __restrict__ xattr,
    const int*  __restrict__ adj,
    const void* __restrict__ W0h, const void* __restrict__ a0h,
    const void* __restrict__ W1h, const void* __restrict__ a1h,
    const void* __restrict__ fc1w, const void* __restrict__ fc1b,
    const void* __restrict__ prew, const void* __restrict__ preb,
    const void* __restrict__ predw, const void* __restrict__ predb,
    const void* __restrict__ varw,  const void* __restrict__ varb,
    float* __restrict__ outy,
    float* __restrict__ outv,
    float* __restrict__ outxc)
{
    __shared__ float s_fc1w[XF * NF];     // 47104 B (f32)
    __shared__ float s_prew[NF * NP];     // 8192 B
    __shared__ float s_fc1b[NF];
    __shared__ float s_aux[52];           // [0:16) preb, [16:32) predw, [32:48) varw, [48] predb, [49] varb
    __shared__ float s_ft[BLK * FSTRIDE]; // per-thread feat[92] + x[23]
    __shared__ unsigned s_rm[BLK * 25];   // per-thread row masks (stride 25, odd)

    const int tid = threadIdx.x;
    const bool f32in = sniff_f32(xattr);

    // ---- stage weights -> f32 in LDS ----
    if (f32in) {
        const float4* s4 = (const float4*)fc1w;
        for (int i = tid; i < (XF * NF) / 4; i += BLK) *(float4*)&s_fc1w[i * 4] = s4[i];
        const float4* p4 = (const float4*)prew;
        for (int i = tid; i < (NF * NP) / 4; i += BLK) *(float4*)&s_prew[i * 4] = p4[i];
    } else {
        const ushort4* s4 = (const ushort4*)fc1w;
        for (int i = tid; i < (XF * NF) / 4; i += BLK) {
            ushort4 u = s4[i];
            *(float4*)&s_fc1w[i * 4] = make_float4(bits2f(u.x), bits2f(u.y), bits2f(u.z), bits2f(u.w));
        }
        const ushort4* p4 = (const ushort4*)prew;
        for (int i = tid; i < (NF * NP) / 4; i += BLK) {
            ushort4 u = p4[i];
            *(float4*)&s_prew[i * 4] = make_float4(bits2f(u.x), bits2f(u.y), bits2f(u.z), bits2f(u.w));
        }
    }
    for (int i = tid; i < NF; i += BLK) s_fc1b[i] = ld1(fc1b, i, f32in);
    if (tid < NP) {
        s_aux[tid]      = ld1(preb, tid, f32in);
        s_aux[16 + tid] = ld1(predw, tid, f32in);
        s_aux[32 + tid] = ld1(varw, tid, f32in);
    }
    if (tid == 0) { s_aux[48] = ld1(predb, 0, f32in); s_aux[49] = ld1(varb, 0, f32in); }
    __syncthreads();

    const int b = blockIdx.x * BLK + tid;
    float* myfeat = &s_ft[tid * FSTRIDE];
    float* myx    = myfeat + XF;
    unsigned* myrm = &s_rm[tid * 25];

    // ---- load node attrs ----
    float x[NN];
    #pragma unroll
    for (int n = 0; n < NN; ++n) {
        float v = ld1(xattr, b * NN + n, f32in);
        x[n] = v; myx[n] = v;
    }

    // ---- build row masks: bit j of myrm[i] = (adj[b][i][j] != 0) ----
    const int* arow = adj + (size_t)b * (NN * NN);
    #pragma unroll 1
    for (int i = 0; i < NN; ++i) {
        unsigned m = 0u;
        #pragma unroll
        for (int j = 0; j < NN; ++j) m |= (arow[i * NN + j] != 0 ? (1u << j) : 0u);
        myrm[i] = m;
    }

    // ---- two attention heads ----
    #pragma unroll 1
    for (int head = 0; head < 2; ++head) {
        const void* Wp = head ? W1h : W0h;
        const void* ap = head ? a1h : a0h;
        const float w0 = ld1(Wp, 0, f32in), w1 = ld1(Wp, 1, f32in);
        const float c1 = w0 * ld1(ap, 0, f32in) + w1 * ld1(ap, 1, f32in);
        const float c2 = w0 * ld1(ap, 2, f32in) + w1 * ld1(ap, 3, f32in);

        float f2v[NN], dcol[NN];
        #pragma unroll
        for (int j = 0; j < NN; ++j) { f2v[j] = x[j] * c2; dcol[j] = 0.0f; }

        // denominator pass: dcol[j] = sum_i exp(masked lrelu(f1_i + f2_j))
        // (no max-subtraction needed: |e| <= ~60 so no f32 overflow; masked -> 0)
        #pragma unroll 1
        for (int i = 0; i < NN; ++i) {
            const float f1i = myx[i] * c1;
            const unsigned rm = myrm[i];
            #pragma unroll
            for (int j = 0; j < NN; ++j) {
                float e = f1i + f2v[j];
                e = e > 0.0f ? e : 0.2f * e;
                float p = ((rm >> j) & 1u) ? __expf(e) : 0.0f;
                dcol[j] += p;
            }
        }

        // scale: scl[j] = x_j / denom_j; empty columns -> uniform 1/23 (matches jax softmax of all -1e20)
        float scl[NN];
        float sbase = 0.0f;
        #pragma unroll
        for (int j = 0; j < NN; ++j) {
            const bool empty = (dcol[j] == 0.0f);
            scl[j] = empty ? 0.0f : x[j] / dcol[j];
            sbase += empty ? x[j] * (1.0f / 23.0f) : 0.0f;
        }

        // accumulate s_i = sum_j att[i][j] * x_j ; features = gelu(W_f * s_i)
        #pragma unroll 1
        for (int i = 0; i < NN; ++i) {
            const float f1i = myx[i] * c1;
            const unsigned rm = myrm[i];
            float s = sbase;
            #pragma unroll
            for (int j = 0; j < NN; ++j) {
                float e = f1i + f2v[j];
                e = e > 0.0f ? e : 0.2f * e;
                float p = ((rm >> j) & 1u) ? __expf(e) : 0.0f;
                s = fmaf(p, scl[j], s);
            }
            myfeat[i * 4 + head * 2 + 0] = geluf(w0 * s);
            myfeat[i * 4 + head * 2 + 1] = geluf(w1 * s);
        }
    }

    // ---- MLP: fc1 (92->128, relu) -> pre (128->16, gelu) -> predict/getvar ----
    float xp[NP];
    #pragma unroll
    for (int t = 0; t < NP; ++t) xp[t] = s_aux[t];

    const size_t xcbase = (size_t)b * NF;
    #pragma unroll 1
    for (int k = 0; k < NF; k += 8) {
        float acc[8];
        #pragma unroll
        for (int q = 0; q < 8; ++q) acc[q] = s_fc1b[k + q];
        #pragma unroll 4
        for (int m = 0; m < XF; ++m) {
            const float fm = myfeat[m];
            const float4 wa = *(const float4*)&s_fc1w[m * NF + k];
            const float4 wb = *(const float4*)&s_fc1w[m * NF + k + 4];
            acc[0] = fmaf(fm, wa.x, acc[0]);
            acc[1] = fmaf(fm, wa.y, acc[1]);
            acc[2] = fmaf(fm, wa.z, acc[2]);
            acc[3] = fmaf(fm, wa.w, acc[3]);
            acc[4] = fmaf(fm, wb.x, acc[4]);
            acc[5] = fmaf(fm, wb.y, acc[5]);
            acc[6] = fmaf(fm, wb.z, acc[6]);
            acc[7] = fmaf(fm, wb.w, acc[7]);
        }
        float o8[8];
        #pragma unroll
        for (int q = 0; q < 8; ++q) {
            const float v = fmaxf(acc[q], 0.0f);
            o8[q] = v;
            const float4 p0 = *(const float4*)&s_prew[(k + q) * NP + 0];
            const float4 p1 = *(const float4*)&s_prew[(k + q) * NP + 4];
            const float4 p2 = *(const float4*)&s_prew[(k + q) * NP + 8];
            const float4 p3 = *(const float4*)&s_prew[(k + q) * NP + 12];
            xp[0]  = fmaf(v, p0.x, xp[0]);
            xp[1]  = fmaf(v, p0.y, xp[1]);
            xp[2]  = fmaf(v, p0.z, xp[2]);
            xp[3]  = fmaf(v, p0.w, xp[3]);
            xp[4]  = fmaf(v, p1.x, xp[4]);
            xp[5]  = fmaf(v, p1.y, xp[5]);
            xp[6]  = fmaf(v, p1.z, xp[6]);
            xp[7]  = fmaf(v, p1.w, xp[7]);
            xp[8]  = fmaf(v, p2.x, xp[8]);
            xp[9]  = fmaf(v, p2.y, xp[9]);
            xp[10] = fmaf(v, p2.z, xp[10]);
            xp[11] = fmaf(v, p2.w, xp[11]);
            xp[12] = fmaf(v, p3.x, xp[12]);
            xp[13] = fmaf(v, p3.y, xp[13]);
            xp[14] = fmaf(v, p3.z, xp[14]);
            xp[15] = fmaf(v, p3.w, xp[15]);
        }
        *(float4*)&outxc[xcbase + k]     = make_float4(o8[0], o8[1], o8[2], o8[3]);
        *(float4*)&outxc[xcbase + k + 4] = make_float4(o8[4], o8[5], o8[6], o8[7]);
    }

    float y = s_aux[48], vv = s_aux[49];
    #pragma unroll
    for (int t = 0; t < NP; ++t) {
        const float g = geluf(xp[t]);
        y  = fmaf(g, s_aux[16 + t], y);
        vv = fmaf(g, s_aux[32 + t], vv);
    }
    outy[b] = fmaxf(y, 0.0f);
    outv[b] = vv;
}

extern "C" void kernel_launch(void* const* d_in, const int* in_sizes, int n_in,
                              void* d_out, int out_size, void* d_ws, size_t ws_size,
                              hipStream_t stream) {
    const void* xattr = d_in[0];
    const int*  adjp  = (const int*)d_in[1];

    const int B = in_sizes[0] / NN;
    float* o = (float*)d_out;
    float* outy  = o;
    float* outv  = o + B;
    float* outxc = o + 2 * (size_t)B;

    gat_fused<<<dim3(B / BLK), dim3(BLK), 0, stream>>>(
        xattr, adjp, d_in[2], d_in[3], d_in[4], d_in[5], d_in[6], d_in[7],
        d_in[8], d_in[9], d_in[10], d_in[11], d_in[12], d_in[13],
        outy, outv, outxc);
}

// Round 5
// 151.006 us; speedup vs baseline: 1.6313x; 1.6313x over previous
//
#include <hip/hip_runtime.h>
#include <hip/hip_bf16.h>

#define NN 23
#define BLK 256
#define SPB 8            // samples per block (one per 32-lane half-wave)

__device__ __forceinline__ float lo2f(unsigned u) { return __uint_as_float(u << 16); }
__device__ __forceinline__ float hi2f(unsigned u) { return __uint_as_float(u & 0xFFFF0000u); }
__device__ __forceinline__ unsigned short f2b(float f) {
    union { __hip_bfloat16 h; unsigned short u; } c; c.h = __float2bfloat16(f); return c.u;
}
__device__ __forceinline__ float geluf(float v) {
    return 0.5f * v * (1.0f + erff(v * 0.70710678118654752f));
}

// 32 lanes per sample: lane l<23 owns attention COLUMN l (softmax dim=1 is
// over rows i -> column sums are lane-local). Numerator rows recovered via
// width-32 butterfly + static select chain. MLP: lane l owns fc1 outputs
// 4l..4l+3 (bf16 weights in LDS, one ds_read_b64 per m).
__global__ __launch_bounds__(BLK, 3) void gat_fused(
    const float* __restrict__ xattr, const int* __restrict__ adj,
    const float* __restrict__ W0,   const float* __restrict__ a0,
    const float* __restrict__ W1,   const float* __restrict__ a1,
    const float* __restrict__ fc1w, const float* __restrict__ fc1b,
    const float* __restrict__ prew, const float* __restrict__ preb,
    const float* __restrict__ predw, const float* __restrict__ predb,
    const float* __restrict__ varw,  const float* __restrict__ varb,
    float* __restrict__ outy, float* __restrict__ outv, float* __restrict__ outxc)
{
    __shared__ unsigned short s_w1[92 * 128];  // fc1w bf16: 23552 B
    __shared__ float s_prew[128 * 17];         // padded stride 17: 8704 B
    __shared__ float s_fc1b[128];
    __shared__ float s_aux[64];   // [0:6) W0,a0  [6:12) W1,a1  [12:28) preb  [28:44) predw  [44:60) varw  [60] predb [61] varb
    __shared__ float s_feat[SPB * 96];         // per-slot feat[92] f32

    const int tid = threadIdx.x;

    // ---- stage weights ----
    for (int i = tid; i < (92 * 128) / 4; i += BLK) {
        float4 w = ((const float4*)fc1w)[i];
        unsigned lo = (unsigned)f2b(w.x) | ((unsigned)f2b(w.y) << 16);
        unsigned hi = (unsigned)f2b(w.z) | ((unsigned)f2b(w.w) << 16);
        *(uint2*)&s_w1[i * 4] = make_uint2(lo, hi);
    }
    for (int i = tid; i < 2048; i += BLK) s_prew[(i >> 4) * 17 + (i & 15)] = prew[i];
    if (tid < 128) s_fc1b[tid] = fc1b[tid];
    if (tid < 16) {
        s_aux[12 + tid] = preb[tid];
        s_aux[28 + tid] = predw[tid];
        s_aux[44 + tid] = varw[tid];
    }
    if (tid == 0) {
        s_aux[0] = W0[0]; s_aux[1] = W0[1];
        s_aux[2] = a0[0]; s_aux[3] = a0[1]; s_aux[4] = a0[2]; s_aux[5] = a0[3];
        s_aux[6] = W1[0]; s_aux[7] = W1[1];
        s_aux[8] = a1[0]; s_aux[9] = a1[1]; s_aux[10] = a1[2]; s_aux[11] = a1[3];
        s_aux[60] = predb[0]; s_aux[61] = varb[0];
    }
    __syncthreads();

    const int slot = tid >> 5;          // 0..7
    const int l    = tid & 31;          // lane within 32-group
    const int s    = blockIdx.x * SPB + slot;   // grid sized exactly B/SPB

    // ---- x load + broadcast ----
    float xl = 0.0f;
    if (l < NN) xl = xattr[s * NN + l];
    float xv[NN];
    #pragma unroll
    for (int i = 0; i < NN; ++i) xv[i] = __shfl(xl, i, 32);

    // ---- column mask: bit i of cm = adj[s][i][l] != 0 (coalesced across lanes) ----
    unsigned cm = 0u;
    if (l < NN) {
        const int* ar = adj + (size_t)s * (NN * NN);
        #pragma unroll
        for (int i = 0; i < NN; ++i) cm |= (ar[i * NN + l] != 0) ? (1u << i) : 0u;
    }

    // ---- two attention heads ----
    float fmine[4];
    #pragma unroll
    for (int h = 0; h < 2; ++h) {
        const float w0 = s_aux[h * 6 + 0], w1 = s_aux[h * 6 + 1];
        const float c1 = w0 * s_aux[h * 6 + 2] + w1 * s_aux[h * 6 + 3];
        const float c2 = w0 * s_aux[h * 6 + 4] + w1 * s_aux[h * 6 + 5];
        const float f2l = xl * c2;

        // p_i = masked exp(lrelu(f1_i + f2_l)); dcol = sum_i p_i (lane-local!)
        float p[NN];
        float dcol = 0.0f;
        #pragma unroll
        for (int i = 0; i < NN; ++i) {
            float e = fmaf(xv[i], c1, f2l);
            e = e > 0.0f ? e : 0.2f * e;
            float pe = ((cm >> i) & 1u) ? __expf(e) : 0.0f;
            p[i] = pe;
            dcol += pe;
        }
        const bool  empty = (dcol == 0.0f);               // lanes >=23: cm=0 -> empty, xl=0 -> no contribution
        const float scl   = empty ? 0.0f : __fdividef(xl, dcol);
        const float ecol  = empty ? xl * (1.0f / 23.0f) : 0.0f;  // jax softmax of all -1e20 -> uniform 1/23

        // t_i(lane) = p_il*scl_l + ecol_l ; s_i = sum over lanes
        float t[NN];
        #pragma unroll
        for (int i = 0; i < NN; ++i) t[i] = fmaf(p[i], scl, ecol);
        #pragma unroll
        for (int r = 1; r < 32; r <<= 1) {
            #pragma unroll
            for (int i = 0; i < NN; ++i) t[i] += __shfl_xor(t[i], r, 32);
        }
        // lane l extracts its own row sum s_l (static select chain)
        float sown = t[0];
        #pragma unroll
        for (int i = 1; i < NN; ++i) sown = (l == i) ? t[i] : sown;

        fmine[h * 2 + 0] = geluf(w0 * sown);
        fmine[h * 2 + 1] = geluf(w1 * sown);
    }

    if (l < NN)
        *(float4*)&s_feat[slot * 96 + l * 4] = make_float4(fmine[0], fmine[1], fmine[2], fmine[3]);
    __syncthreads();

    // ---- fc1: lane l owns outputs k = 4l..4l+3 ----
    const float* fL = &s_feat[slot * 96];
    float ac0 = s_fc1b[4 * l + 0], ac1 = s_fc1b[4 * l + 1];
    float ac2 = s_fc1b[4 * l + 2], ac3 = s_fc1b[4 * l + 3];
    #pragma unroll
    for (int mq = 0; mq < 23; ++mq) {
        const float4 f4 = *(const float4*)&fL[mq * 4];
        #pragma unroll
        for (int u = 0; u < 4; ++u) {
            const float f = (u == 0) ? f4.x : (u == 1) ? f4.y : (u == 2) ? f4.z : f4.w;
            const uint2 wb = *(const uint2*)&s_w1[(mq * 4 + u) * 128 + 4 * l];
            ac0 = fmaf(f, lo2f(wb.x), ac0);
            ac1 = fmaf(f, hi2f(wb.x), ac1);
            ac2 = fmaf(f, lo2f(wb.y), ac2);
            ac3 = fmaf(f, hi2f(wb.y), ac3);
        }
    }
    const float r0 = fmaxf(ac0, 0.0f), r1 = fmaxf(ac1, 0.0f);
    const float r2 = fmaxf(ac2, 0.0f), r3 = fmaxf(ac3, 0.0f);
    *(float4*)&outxc[(size_t)s * 128 + 4 * l] = make_float4(r0, r1, r2, r3);

    // ---- pre (128->16): partials over own 4 k, butterfly-reduce ----
    float xp[16];
    #pragma unroll
    for (int t2 = 0; t2 < 16; ++t2) xp[t2] = 0.0f;
    #pragma unroll
    for (int c = 0; c < 4; ++c) {
        const float rr = (c == 0) ? r0 : (c == 1) ? r1 : (c == 2) ? r2 : r3;
        const float* pr = &s_prew[(4 * l + c) * 17];
        #pragma unroll
        for (int t2 = 0; t2 < 16; ++t2) xp[t2] = fmaf(rr, pr[t2], xp[t2]);
    }
    #pragma unroll
    for (int r = 1; r < 32; r <<= 1) {
        #pragma unroll
        for (int t2 = 0; t2 < 16; ++t2) xp[t2] += __shfl_xor(xp[t2], r, 32);
    }

    // ---- epilogue: gelu(pre) -> predict / getvar ----
    float y = s_aux[60], vv = s_aux[61];
    #pragma unroll
    for (int t2 = 0; t2 < 16; ++t2) {
        const float g = geluf(xp[t2] + s_aux[12 + t2]);
        y  = fmaf(g, s_aux[28 + t2], y);
        vv = fmaf(g, s_aux[44 + t2], vv);
    }
    if (l == 0) {
        outy[s] = fmaxf(y, 0.0f);
        outv[s] = vv;
    }
}

extern "C" void kernel_launch(void* const* d_in, const int* in_sizes, int n_in,
                              void* d_out, int out_size, void* d_ws, size_t ws_size,
                              hipStream_t stream) {
    const float* xattr = (const float*)d_in[0];
    const int*   adjp  = (const int*)d_in[1];

    const int B = in_sizes[0] / NN;   // 16384 (divisible by SPB)
    float* o = (float*)d_out;
    float* outy  = o;
    float* outv  = o + B;
    float* outxc = o + 2 * (size_t)B;

    gat_fused<<<dim3(B / SPB), dim3(BLK), 0, stream>>>(
        xattr, adjp,
        (const float*)d_in[2], (const float*)d_in[3],
        (const float*)d_in[4], (const float*)d_in[5],
        (const float*)d_in[6], (const float*)d_in[7],
        (const float*)d_in[8], (const float*)d_in[9],
        (const float*)d_in[10], (const float*)d_in[11],
        (const float*)d_in[12], (const float*)d_in[13],
        outy, outv, outxc);
}

// Round 7
// 139.606 us; speedup vs baseline: 1.7645x; 1.0817x over previous
//
#include <hip/hip_runtime.h>
#include <hip/hip_bf16.h>

#define NN 23
#define BLK 256
#define SPB 8            // samples per block (one per 32-lane group)

__device__ __forceinline__ float lo2f(unsigned u) { return __uint_as_float(u << 16); }
__device__ __forceinline__ float hi2f(unsigned u) { return __uint_as_float(u & 0xFFFF0000u); }
__device__ __forceinline__ unsigned short f2b(float f) {
    union { __hip_bfloat16 h; unsigned short u; } c; c.h = __float2bfloat16(f); return c.u;
}
__device__ __forceinline__ float geluf(float v) {
    return 0.5f * v * (1.0f + erff(v * 0.70710678118654752f));
}

// 32 lanes/sample. Lane l<23 owns attention COLUMN l: softmax dim=1 (over rows)
// -> denominator is lane-local. Numerator: lane i recomputes row i using a
// ballot-transposed row mask + shfl-broadcast column scales (no butterflies).
// fc1: lane l owns outputs 4l..4l+3 (bf16 weights in LDS). pre/predict/getvar:
// reduce-scatter so each lane finishes exactly one pre-column (one gelu).
__global__ __launch_bounds__(BLK, 5) void gat_fused(
    const float* __restrict__ xattr, const int* __restrict__ adj,
    const float* __restrict__ W0,   const float* __restrict__ a0,
    const float* __restrict__ W1,   const float* __restrict__ a1,
    const float* __restrict__ fc1w, const float* __restrict__ fc1b,
    const float* __restrict__ prew, const float* __restrict__ preb,
    const float* __restrict__ predw, const float* __restrict__ predb,
    const float* __restrict__ varw,  const float* __restrict__ varb,
    float* __restrict__ outy, float* __restrict__ outv, float* __restrict__ outxc)
{
    __shared__ unsigned short s_w1[92 * 128];  // fc1w bf16: 23552 B
    __shared__ unsigned s_pw[128 * 9];         // prew bf16 pairs, stride 9: 4608 B
    __shared__ float s_fc1b[128];              // 512 B
    __shared__ float s_aux[64];                // 256 B: [0:6) W0|a0 [6:12) W1|a1 [12:28) preb [28:44) predw [44:60) varw [60] predb [61] varb
    __shared__ float s_feat[SPB * 96];         // 3072 B  -> total 32000 B => 5 blocks/CU

    const int tid = threadIdx.x;

    // ---- stage weights ----
    for (int i = tid; i < (92 * 128) / 4; i += BLK) {
        float4 w = ((const float4*)fc1w)[i];
        unsigned lo = (unsigned)f2b(w.x) | ((unsigned)f2b(w.y) << 16);
        unsigned hi = (unsigned)f2b(w.z) | ((unsigned)f2b(w.w) << 16);
        *(uint2*)&s_w1[i * 4] = make_uint2(lo, hi);
    }
    for (int i = tid; i < 1024; i += BLK) {    // prew: 128x16 f32 -> [128][8] packed bf16 pairs, row stride 9
        float2 w = ((const float2*)prew)[i];
        s_pw[(i >> 3) * 9 + (i & 7)] = (unsigned)f2b(w.x) | ((unsigned)f2b(w.y) << 16);
    }
    if (tid < 128) s_fc1b[tid] = fc1b[tid];
    if (tid < 16) {
        s_aux[12 + tid] = preb[tid];
        s_aux[28 + tid] = predw[tid];
        s_aux[44 + tid] = varw[tid];
    }
    if (tid == 0) {
        s_aux[0] = W0[0]; s_aux[1] = W0[1];
        s_aux[2] = a0[0]; s_aux[3] = a0[1]; s_aux[4] = a0[2]; s_aux[5] = a0[3];
        s_aux[6] = W1[0]; s_aux[7] = W1[1];
        s_aux[8] = a1[0]; s_aux[9] = a1[1]; s_aux[10] = a1[2]; s_aux[11] = a1[3];
        s_aux[60] = predb[0]; s_aux[61] = varb[0];
    }
    __syncthreads();

    const int slot = tid >> 5;
    const int l    = tid & 31;
    const int s    = blockIdx.x * SPB + slot;

    // ---- x load + broadcast ----
    float xl = 0.0f;
    if (l < NN) xl = xattr[s * NN + l];
    float xv[NN];
    #pragma unroll
    for (int i = 0; i < NN; ++i) xv[i] = __shfl(xl, i, 32);

    // ---- column mask (coalesced): bit i of cm = adj[s][i][l] != 0 ----
    unsigned cm = 0u;
    if (l < NN) {
        const int* ar = adj + (size_t)s * (NN * NN);
        #pragma unroll
        for (int i = 0; i < NN; ++i) cm |= (ar[i * NN + l] != 0) ? (1u << i) : 0u;
    }

    // ---- row mask via ballot transpose: lane i gets bit j = adj[i][j] ----
    unsigned rm = 0u;
    #pragma unroll
    for (int i = 0; i < NN; ++i) {
        unsigned long long bal = __ballot((cm >> i) & 1u);
        unsigned half = (unsigned)(bal >> (tid & 32));
        rm = (l == i) ? half : rm;
    }
    // empty-column mask (adjacency-only, head-independent)
    unsigned em;
    {
        unsigned long long bal = __ballot(cm == 0u);
        em = ((unsigned)(bal >> (tid & 32))) & 0x7FFFFFu;
    }
    float sbase = 0.0f;
    #pragma unroll
    for (int j = 0; j < NN; ++j) sbase += ((em >> j) & 1u) ? xv[j] : 0.0f;
    sbase *= (1.0f / 23.0f);   // jax softmax of all -1e20 -> uniform 1/23

    // ---- two attention heads ----
    float fmine[4];
    #pragma unroll
    for (int h = 0; h < 2; ++h) {
        const float w0 = s_aux[h * 6 + 0], w1 = s_aux[h * 6 + 1];
        const float c1 = w0 * s_aux[h * 6 + 2] + w1 * s_aux[h * 6 + 3];
        const float c2 = w0 * s_aux[h * 6 + 4] + w1 * s_aux[h * 6 + 5];

        // column pass: dcol = sum_i masked exp(lrelu(c1*x_i + c2*x_l))  (lane-local)
        const float f2l = xl * c2;
        float dcol = 0.0f;
        #pragma unroll
        for (int i = 0; i < NN; ++i) {
            float e = fmaf(xv[i], c1, f2l);
            e = fmaxf(e, 0.2f * e);                     // leakyrelu
            float t = ((cm >> i) & 1u) ? 1.0f : 0.0f;
            dcol = fmaf(__expf(e), t, dcol);
        }
        const float scl = (cm == 0u) ? 0.0f : __fdividef(xl, dcol);

        // broadcast column scales
        float sclv[NN];
        #pragma unroll
        for (int j = 0; j < NN; ++j) sclv[j] = __shfl(scl, j, 32);

        // row pass: s_l = sbase + sum_j masked exp(lrelu(c1*x_l + c2*x_j)) * scl_j
        const float f1 = xl * c1;
        float sown = sbase;
        #pragma unroll
        for (int j = 0; j < NN; ++j) {
            float e = fmaf(xv[j], c2, f1);
            e = fmaxf(e, 0.2f * e);
            float t = ((rm >> j) & 1u) ? sclv[j] : 0.0f;
            sown = fmaf(__expf(e), t, sown);
        }

        fmine[h * 2 + 0] = geluf(w0 * sown);
        fmine[h * 2 + 1] = geluf(w1 * sown);
    }

    if (l < NN)
        *(float4*)&s_feat[slot * 96 + l * 4] = make_float4(fmine[0], fmine[1], fmine[2], fmine[3]);
    __syncthreads();

    // ---- fc1: lane l owns outputs k = 4l..4l+3 (bf16 weights, ds_read_b64) ----
    const float* fL = &s_feat[slot * 96];
    const float4 b4 = *(const float4*)&s_fc1b[4 * l];
    float ac0 = b4.x, ac1 = b4.y, ac2 = b4.z, ac3 = b4.w;
    #pragma unroll
    for (int mq = 0; mq < 23; ++mq) {
        const float4 f4 = *(const float4*)&fL[mq * 4];   // same-addr broadcast per group
        #pragma unroll
        for (int u = 0; u < 4; ++u) {
            const float f = (u == 0) ? f4.x : (u == 1) ? f4.y : (u == 2) ? f4.z : f4.w;
            const uint2 wb = *(const uint2*)&s_w1[(mq * 4 + u) * 128 + 4 * l];
            ac0 = fmaf(f, lo2f(wb.x), ac0);
            ac1 = fmaf(f, hi2f(wb.x), ac1);
            ac2 = fmaf(f, lo2f(wb.y), ac2);
            ac3 = fmaf(f, hi2f(wb.y), ac3);
        }
    }
    const float r0 = fmaxf(ac0, 0.0f), r1 = fmaxf(ac1, 0.0f);
    const float r2 = fmaxf(ac2, 0.0f), r3 = fmaxf(ac3, 0.0f);
    *(float4*)&outxc[(size_t)s * 128 + 4 * l] = make_float4(r0, r1, r2, r3);

    // ---- pre partials: xp[t] += r_c * prew[4l+c][t] ----
    float xp[16];
    #pragma unroll
    for (int t = 0; t < 16; ++t) xp[t] = 0.0f;
    #pragma unroll
    for (int c = 0; c < 4; ++c) {
        const float rr = (c == 0) ? r0 : (c == 1) ? r1 : (c == 2) ? r2 : r3;
        const unsigned* pw = &s_pw[(4 * l + c) * 9];
        #pragma unroll
        for (int u = 0; u < 8; ++u) {
            const unsigned w = pw[u];
            xp[2 * u + 0] = fmaf(rr, lo2f(w), xp[2 * u + 0]);
            xp[2 * u + 1] = fmaf(rr, hi2f(w), xp[2 * u + 1]);
        }
    }

    // ---- reduce-scatter: lane l ends with full sum of pre-column (l&15) ----
    #pragma unroll
    for (int b = 3; b >= 0; --b) {
        const int m = 1 << b;
        #pragma unroll
        for (int k = 0; k < (1 << b); ++k) {
            float mine  = (l & m) ? xp[(1 << b) + k] : xp[k];
            float other = (l & m) ? xp[k] : xp[(1 << b) + k];
            xp[k] = mine + __shfl_xor(other, m, 32);
        }
    }
    xp[0] += __shfl_xor(xp[0], 16, 32);

    // ---- epilogue: one gelu per lane, then 16-lane reduce for y/var ----
    const int t2 = l & 15;
    const float g = geluf(xp[0] + s_aux[12 + t2]);
    float yp = g * s_aux[28 + t2];
    float vp = g * s_aux[44 + t2];
    #pragma unroll
    for (int m = 1; m < 16; m <<= 1) {
        yp += __shfl_xor(yp, m, 32);
        vp += __shfl_xor(vp, m, 32);
    }
    if (l == 0) {
        outy[s] = fmaxf(yp + s_aux[60], 0.0f);
        outv[s] = vp + s_aux[61];
    }
}

extern "C" void kernel_launch(void* const* d_in, const int* in_sizes, int n_in,
                              void* d_out, int out_size, void* d_ws, size_t ws_size,
                              hipStream_t stream) {
    const float* xattr = (const float*)d_in[0];
    const int*   adjp  = (const int*)d_in[1];

    const int B = in_sizes[0] / NN;   // 16384
    float* o = (float*)d_out;
    float* outy  = o;
    float* outv  = o + B;
    float* outxc = o + 2 * (size_t)B;

    gat_fused<<<dim3(B / SPB), dim3(BLK), 0, stream>>>(
        xattr, adjp,
        (const float*)d_in[2], (const float*)d_in[3],
        (const float*)d_in[4], (const float*)d_in[5],
        (const float*)d_in[6], (const float*)d_in[7],
        (const float*)d_in[8], (const float*)d_in[9],
        (const float*)d_in[10], (const float*)d_in[11],
        (const float*)d_in[12], (const float*)d_in[13],
        outy, outv, outxc);
}

// Round 8
// 119.783 us; speedup vs baseline: 2.0565x; 1.1655x over previous
//
#include <hip/hip_runtime.h>
#include <hip/hip_bf16.h>

#define NN 23
#define BLK 256
#define SPB 16           // samples per block
#define WST 104          // row stride (bf16 elems) for s_w1t / s_feat  (banks spread, 16B-aligned)
#define XST 136          // row stride for s_xc / s_pwt

typedef __attribute__((ext_vector_type(8))) short bf16x8;
typedef __attribute__((ext_vector_type(4))) float f32x4;

__device__ __forceinline__ unsigned short f2b(float f) {
    union { __hip_bfloat16 h; unsigned short u; } c; c.h = __float2bfloat16(f); return c.u;
}
__device__ __forceinline__ float geluf(float v) {
    return 0.5f * v * (1.0f + erff(v * 0.70710678118654752f));
}

// 16 samples/block. Attention: 8x 32-lane groups, 2 samples each (ballot-mask
// + lane-local column softmax + row recompute). fc1: MFMA 16x16x32 bf16,
// M=16 samples, N=128, K=96 (padded). pre: MFMA M=16,N=16,K=128 on wave 0.
__global__ __launch_bounds__(BLK, 4) void gat_fused(
    const float* __restrict__ xattr, const int* __restrict__ adj,
    const float* __restrict__ W0,   const float* __restrict__ a0,
    const float* __restrict__ W1,   const float* __restrict__ a1,
    const float* __restrict__ fc1w, const float* __restrict__ fc1b,
    const float* __restrict__ prew, const float* __restrict__ preb,
    const float* __restrict__ predw, const float* __restrict__ predb,
    const float* __restrict__ varw,  const float* __restrict__ varb,
    float* __restrict__ outy, float* __restrict__ outv, float* __restrict__ outxc)
{
    __shared__ unsigned short s_w1t[128 * WST]; // fc1w^T bf16 [n][k]: 26624 B
    __shared__ unsigned short s_feat[SPB * WST];// feat bf16 [s][k]:    3328 B
    __shared__ unsigned short s_xc[SPB * XST];  // xc bf16 [s][k]:      4352 B
    __shared__ unsigned short s_pwt[16 * XST];  // prew^T bf16 [t][k]:  4352 B
    __shared__ float s_fc1b[128];               // 512 B
    __shared__ float s_aux[64];                 // [0:6) W0|a0 [6:12) W1|a1 [12:28) preb [28:44) predw [44:60) varw [60] predb [61] varb

    const int tid = threadIdx.x;

    // ---- stage: fc1w [92][128] f32 -> s_w1t[n][m] bf16 (transpose) ----
    for (int i = tid; i < 92 * 128; i += BLK) {
        const int m = i >> 7, n = i & 127;
        s_w1t[n * WST + m] = f2b(fc1w[i]);
    }
    for (int i = tid; i < 256; i += BLK) {      // zero-pad k=92..95
        const int n = i >> 1, u = i & 1;
        *(unsigned*)&s_w1t[n * WST + 92 + 2 * u] = 0u;
    }
    if (tid < 32) {                              // s_feat pad rows
        const int r = tid >> 1, u = tid & 1;
        *(unsigned*)&s_feat[r * WST + 92 + 2 * u] = 0u;
    }
    // prew [128][16] f32 -> s_pwt[t][k] bf16 (transpose)
    for (int i = tid; i < 2048; i += BLK) {
        const int k = i >> 4, t = i & 15;
        s_pwt[t * XST + k] = f2b(prew[i]);
    }
    if (tid < 128) s_fc1b[tid] = fc1b[tid];
    if (tid < 16) {
        s_aux[12 + tid] = preb[tid];
        s_aux[28 + tid] = predw[tid];
        s_aux[44 + tid] = varw[tid];
    }
    if (tid == 0) {
        s_aux[0] = W0[0]; s_aux[1] = W0[1];
        s_aux[2] = a0[0]; s_aux[3] = a0[1]; s_aux[4] = a0[2]; s_aux[5] = a0[3];
        s_aux[6] = W1[0]; s_aux[7] = W1[1];
        s_aux[8] = a1[0]; s_aux[9] = a1[1]; s_aux[10] = a1[2]; s_aux[11] = a1[3];
        s_aux[60] = predb[0]; s_aux[61] = varb[0];
    }
    __syncthreads();

    const int group = tid >> 5;
    const int l     = tid & 31;

    // ---- attention: 2 samples per 32-lane group ----
    #pragma unroll 1
    for (int rnd = 0; rnd < 2; ++rnd) {
        const int sl = group * 2 + rnd;              // local sample 0..15
        const int s  = blockIdx.x * SPB + sl;

        float xl = 0.0f;
        if (l < NN) xl = xattr[s * NN + l];
        float xv[NN];
        #pragma unroll
        for (int i = 0; i < NN; ++i) xv[i] = __shfl(xl, i, 32);

        unsigned cm = 0u;
        if (l < NN) {
            const int* ar = adj + (size_t)s * (NN * NN);
            #pragma unroll
            for (int i = 0; i < NN; ++i) cm |= (ar[i * NN + l] != 0) ? (1u << i) : 0u;
        }
        unsigned rm = 0u;
        #pragma unroll
        for (int i = 0; i < NN; ++i) {
            unsigned long long bal = __ballot((cm >> i) & 1u);
            unsigned half = (unsigned)(bal >> (tid & 32));
            rm = (l == i) ? half : rm;
        }
        unsigned em;
        {
            unsigned long long bal = __ballot(cm == 0u);
            em = ((unsigned)(bal >> (tid & 32))) & 0x7FFFFFu;
        }
        float sbase = 0.0f;
        #pragma unroll
        for (int j = 0; j < NN; ++j) sbase += ((em >> j) & 1u) ? xv[j] : 0.0f;
        sbase *= (1.0f / 23.0f);

        float fmine[4];
        #pragma unroll
        for (int h = 0; h < 2; ++h) {
            const float w0 = s_aux[h * 6 + 0], w1 = s_aux[h * 6 + 1];
            const float c1 = w0 * s_aux[h * 6 + 2] + w1 * s_aux[h * 6 + 3];
            const float c2 = w0 * s_aux[h * 6 + 4] + w1 * s_aux[h * 6 + 5];

            const float f2l = xl * c2;
            float dcol = 0.0f;
            #pragma unroll
            for (int i = 0; i < NN; ++i) {
                float e = fmaf(xv[i], c1, f2l);
                e = fmaxf(e, 0.2f * e);
                float t = ((cm >> i) & 1u) ? 1.0f : 0.0f;
                dcol = fmaf(__expf(e), t, dcol);
            }
            const float scl = (cm == 0u) ? 0.0f : __fdividef(xl, dcol);

            float sclv[NN];
            #pragma unroll
            for (int j = 0; j < NN; ++j) sclv[j] = __shfl(scl, j, 32);

            const float f1 = xl * c1;
            float sown = sbase;
            #pragma unroll
            for (int j = 0; j < NN; ++j) {
                float e = fmaf(xv[j], c2, f1);
                e = fmaxf(e, 0.2f * e);
                float t = ((rm >> j) & 1u) ? sclv[j] : 0.0f;
                sown = fmaf(__expf(e), t, sown);
            }
            fmine[h * 2 + 0] = geluf(w0 * sown);
            fmine[h * 2 + 1] = geluf(w1 * sown);
        }

        if (l < NN) {
            unsigned lo = (unsigned)f2b(fmine[0]) | ((unsigned)f2b(fmine[1]) << 16);
            unsigned hi = (unsigned)f2b(fmine[2]) | ((unsigned)f2b(fmine[3]) << 16);
            *(uint2*)&s_feat[sl * WST + 4 * l] = make_uint2(lo, hi);
        }
    }
    __syncthreads();

    // ---- fc1 via MFMA: wave w owns output cols [32w, 32w+32) ----
    {
        const int wave = tid >> 6;
        const int lane = tid & 63;
        const int q    = lane >> 4;      // k-chunk / C row-group
        const int c16  = lane & 15;

        f32x4 acc0 = {0.f, 0.f, 0.f, 0.f};
        f32x4 acc1 = {0.f, 0.f, 0.f, 0.f};
        const int n0 = 32 * wave + c16;
        const int n1 = n0 + 16;
        #pragma unroll
        for (int t = 0; t < 3; ++t) {
            const bf16x8 a  = *(const bf16x8*)&s_feat[c16 * WST + 32 * t + 8 * q];
            const bf16x8 b0 = *(const bf16x8*)&s_w1t[n0 * WST + 32 * t + 8 * q];
            const bf16x8 b1 = *(const bf16x8*)&s_w1t[n1 * WST + 32 * t + 8 * q];
            acc0 = __builtin_amdgcn_mfma_f32_16x16x32_bf16(a, b0, acc0, 0, 0, 0);
            acc1 = __builtin_amdgcn_mfma_f32_16x16x32_bf16(a, b1, acc1, 0, 0, 0);
        }
        const float bia0 = s_fc1b[n0], bia1 = s_fc1b[n1];
        const size_t gbase = (size_t)blockIdx.x * SPB * 128;
        #pragma unroll
        for (int r = 0; r < 4; ++r) {
            const int srow = 4 * q + r;
            const float v0 = fmaxf(acc0[r] + bia0, 0.0f);
            const float v1 = fmaxf(acc1[r] + bia1, 0.0f);
            outxc[gbase + (size_t)srow * 128 + n0] = v0;
            outxc[gbase + (size_t)srow * 128 + n1] = v1;
            s_xc[srow * XST + n0] = f2b(v0);
            s_xc[srow * XST + n1] = f2b(v1);
        }
    }
    __syncthreads();

    // ---- pre via MFMA (wave 0) + epilogue ----
    if (tid < 64) {
        const int q   = tid >> 4;
        const int c16 = tid & 15;   // pre-output index t'
        f32x4 acc = {0.f, 0.f, 0.f, 0.f};
        #pragma unroll
        for (int t = 0; t < 4; ++t) {
            const bf16x8 a = *(const bf16x8*)&s_xc[c16 * XST + 32 * t + 8 * q];
            const bf16x8 b = *(const bf16x8*)&s_pwt[c16 * XST + 32 * t + 8 * q];
            acc = __builtin_amdgcn_mfma_f32_16x16x32_bf16(a, b, acc, 0, 0, 0);
        }
        const float pb = s_aux[12 + c16], pw = s_aux[28 + c16], vw = s_aux[44 + c16];
        float yp[4], vp[4];
        #pragma unroll
        for (int r = 0; r < 4; ++r) {
            const float g = geluf(acc[r] + pb);
            yp[r] = g * pw;
            vp[r] = g * vw;
        }
        #pragma unroll
        for (int m = 1; m < 16; m <<= 1) {
            #pragma unroll
            for (int r = 0; r < 4; ++r) {
                yp[r] += __shfl_xor(yp[r], m, 64);
                vp[r] += __shfl_xor(vp[r], m, 64);
            }
        }
        if (c16 == 0) {
            const int sb = blockIdx.x * SPB + 4 * q;
            #pragma unroll
            for (int r = 0; r < 4; ++r) {
                outy[sb + r] = fmaxf(yp[r] + s_aux[60], 0.0f);
                outv[sb + r] = vp[r] + s_aux[61];
            }
        }
    }
}

extern "C" void kernel_launch(void* const* d_in, const int* in_sizes, int n_in,
                              void* d_out, int out_size, void* d_ws, size_t ws_size,
                              hipStream_t stream) {
    const float* xattr = (const float*)d_in[0];
    const int*   adjp  = (const int*)d_in[1];

    const int B = in_sizes[0] / NN;   // 16384
    float* o = (float*)d_out;
    float* outy  = o;
    float* outv  = o + B;
    float* outxc = o + 2 * (size_t)B;

    gat_fused<<<dim3(B / SPB), dim3(BLK), 0, stream>>>(
        xattr, adjp,
        (const float*)d_in[2], (const float*)d_in[3],
        (const float*)d_in[4], (const float*)d_in[5],
        (const float*)d_in[6], (const float*)d_in[7],
        (const float*)d_in[8], (const float*)d_in[9],
        (const float*)d_in[10], (const float*)d_in[11],
        (const float*)d_in[12], (const float*)d_in[13],
        outy, outv, outxc);
}